// Round 4
// baseline (46.984 us; speedup 1.0000x reference)
//
#include <hip/hip_runtime.h>

#define Cc 8
#define Hh 128
#define Ww 128
#define Nn 64
#define Bb 8
#define Dd 169            // (C+2)*C + C + C*C + C + C + 1
#define HW (Hh * Ww)
#define SPLIT 4           // blocks per (b,n)
#define PXB (HW / SPLIT)  // 4096 pixels per block
#define ITERS (PXB / (256 * 4))  // 4 iterations of 4 px per thread

#define INV128 (1.0f / 128.0f)

__device__ __forceinline__ float pick(float4 v, int j) {
    return j == 0 ? v.x : j == 1 ? v.y : j == 2 ? v.z : v.w;
}

// force a block-uniform value into an SGPR
__device__ __forceinline__ float rfl(float x) {
    return __uint_as_float(__builtin_amdgcn_readfirstlane(__float_as_uint(x)));
}

__global__ __launch_bounds__(256)
__attribute__((amdgpu_waves_per_eu(3, 8)))   // VGPR budget 168: W2/W3 stay register-resident
void seg_dice_main(const float* __restrict__ seg_feat,
                   const float* __restrict__ conv_weight,
                   const float* __restrict__ mask,
                   const int*   __restrict__ ind,
                   const float* __restrict__ target,
                   float* __restrict__ ws) {
    const int blk   = blockIdx.x;
    const int bn    = blk >> 2;          // / SPLIT
    const int chunk = blk & (SPLIT - 1);
    const int b     = bn >> 6;
    const int tid   = threadIdx.x;

    __shared__ float w_s[Dd];
    const int ind_bn = ind[bn];

    // gather weight vector: conv_weight[b, d, ind]
    for (int i = tid; i < Dd; i += 256)
        w_s[i] = conv_weight[(size_t)b * Dd * HW + (size_t)i * HW + ind_bn];
    __syncthreads();

    // ---- W1 (80 vals) -> SGPRs via readfirstlane (block-uniform) ----
    float W1s[8][10];
    #pragma unroll
    for (int o = 0; o < 8; ++o)
        #pragma unroll
        for (int i = 0; i < 10; ++i) W1s[o][i] = rfl(w_s[o * 10 + i]);

    // ---- remaining 89 weights -> VGPRs ----
    float B1[8], W2[8][8], B2[8], W3[8];
    #pragma unroll
    for (int o = 0; o < 8; ++o) {
        B1[o] = w_s[80 + o];
        #pragma unroll
        for (int i = 0; i < 8; ++i) W2[o][i] = w_s[88 + o * 8 + i];
        B2[o] = w_s[152 + o];
        W3[o] = w_s[160 + o];
    }
    const float B3 = w_s[168];

    // ---- kill the LDS copy: weights can no longer be re-read from LDS,
    //      so the values above MUST stay in registers through the loop ----
    __syncthreads();
    if (tid < Dd) w_s[tid] = 0.0f;
    __syncthreads();

    const float m  = mask[bn];
    const float x0 = (float)(ind_bn & (Ww - 1));
    const float y0 = (float)(ind_bn >> 7);

    const float* seg_b  = seg_feat + (size_t)b * Cc * HW;
    const float* tgt_bn = target   + (size_t)bn * HW;

    float inter = 0.f, ps = 0.f, ts = 0.f;
    const int pbase = chunk * PXB + (tid << 2);

    #pragma unroll 1
    for (int it = 0; it < ITERS; ++it) {
        const int p = pbase + (it << 10);

        const float4 t4 = *(const float4*)(tgt_bn + p);
        float4 f4[8];
        #pragma unroll
        for (int c = 0; c < 8; ++c) f4[c] = *(const float4*)(seg_b + c * HW + p);

        const float yr = ((float)(p >> 7)        - y0) * INV128;
        const float xb = ((float)(p & (Ww - 1)) - x0) * INV128;

        // bias + y-term shared by the 4 pixels of this row segment
        float base1[8];
        #pragma unroll
        for (int o = 0; o < 8; ++o) base1[o] = fmaf(W1s[o][9], yr, B1[o]);

        #pragma unroll
        for (int j = 0; j < 4; ++j) {
            const float xr = xb + (float)j * INV128;

            float h1[8];
            #pragma unroll
            for (int o = 0; o < 8; ++o) {
                float a = fmaf(W1s[o][8], xr, base1[o]);
                #pragma unroll
                for (int c = 0; c < 8; ++c) a = fmaf(W1s[o][c], pick(f4[c], j), a);
                h1[o] = fmaxf(a, 0.f);
            }
            float h2[8];
            #pragma unroll
            for (int o = 0; o < 8; ++o) {
                float a = B2[o];
                #pragma unroll
                for (int c = 0; c < 8; ++c) a = fmaf(W2[o][c], h1[c], a);
                h2[o] = fmaxf(a, 0.f);
            }
            float z = B3;
            #pragma unroll
            for (int c = 0; c < 8; ++c) z = fmaf(W3[c], h2[c], z);

            const float o_ = __builtin_amdgcn_rcpf(1.f + __expf(-z));
            const float tv = pick(t4, j);
            inter = fmaf(o_, tv, inter);
            ps    = fmaf(o_, o_, ps);
            ts    = fmaf(tv, tv, ts);
        }
    }

    const float m2 = m * m;
    inter *= m2; ps *= m2; ts *= m2;

    // wave reduce then cross-wave via LDS
    #pragma unroll
    for (int off = 32; off > 0; off >>= 1) {
        inter += __shfl_down(inter, off);
        ps    += __shfl_down(ps,    off);
        ts    += __shfl_down(ts,    off);
    }
    __shared__ float red[3][4];
    const int wave = tid >> 6;
    if ((tid & 63) == 0) { red[0][wave] = inter; red[1][wave] = ps; red[2][wave] = ts; }
    __syncthreads();
    if (tid == 0) {
        const int lb = (bn & 63) * SPLIT + chunk;   // 0..255 within batch b
        ws[(b * 3 + 0) * 256 + lb] = red[0][0] + red[0][1] + red[0][2] + red[0][3];
        ws[(b * 3 + 1) * 256 + lb] = red[1][0] + red[1][1] + red[1][2] + red[1][3];
        ws[(b * 3 + 2) * 256 + lb] = red[2][0] + red[2][1] + red[2][2] + red[2][3];
    }
}

// deterministic epilogue: 24 series (8 b x 3 comps) x 256 partials
__global__ void seg_dice_final(const float* __restrict__ ws, float* __restrict__ out) {
    __shared__ float red[24][4];
    const int tid = threadIdx.x;  // 128 threads
    if (tid < 96) {
        const int series = tid >> 2;   // 0..23
        const int part   = tid & 3;    // 0..3
        const float4* p = (const float4*)(ws + series * 256 + part * 64);
        float s = 0.f;
        #pragma unroll
        for (int i = 0; i < 16; ++i) { const float4 v = p[i]; s += (v.x + v.y) + (v.z + v.w); }
        red[series][part] = s;
    }
    __syncthreads();
    if (tid == 0) {
        float acc = 0.f;
        #pragma unroll
        for (int b = 0; b < Bb; ++b) {
            const float inter = red[b*3+0][0] + red[b*3+0][1] + red[b*3+0][2] + red[b*3+0][3];
            const float p2    = red[b*3+1][0] + red[b*3+1][1] + red[b*3+1][2] + red[b*3+1][3];
            const float t2    = red[b*3+2][0] + red[b*3+2][1] + red[b*3+2][2] + red[b*3+2][3];
            acc += 1.0f - (2.0f * inter + 1.0f) / (p2 + t2 + 1.0f);
        }
        out[0] = acc * (1.0f / (float)Bb);
    }
}

extern "C" void kernel_launch(void* const* d_in, const int* in_sizes, int n_in,
                              void* d_out, int out_size, void* d_ws, size_t ws_size,
                              hipStream_t stream) {
    const float* seg_feat    = (const float*)d_in[0];
    const float* conv_weight = (const float*)d_in[1];
    const float* mask        = (const float*)d_in[2];
    const int*   ind         = (const int*)d_in[3];
    const float* target      = (const float*)d_in[4];
    float* out = (float*)d_out;
    float* ws  = (float*)d_ws;

    seg_dice_main<<<Bb * Nn * SPLIT, 256, 0, stream>>>(seg_feat, conv_weight, mask, ind, target, ws);
    seg_dice_final<<<1, 128, 0, stream>>>(ws, out);
}

// Round 7
// 39.915 us; speedup vs baseline: 1.1771x; 1.1771x over previous
//
#include <hip/hip_runtime.h>

#define Cc 8
#define Hh 128
#define Ww 128
#define Nn 64
#define Bb 8
#define Dd 169            // (C+2)*C + C + C*C + C + C + 1
#define HW (Hh * Ww)
#define CHUNKS 16         // blocks per (b,n)
#define NBLK (Bb * Nn * CHUNKS)   // 8192
#define PXB (HW / CHUNKS)         // 1024 px per block; 4 px per thread, no loop

#define INV128 (1.0f / 128.0f)

typedef __fp16 f16x2 __attribute__((ext_vector_type(2)));

static __device__ __forceinline__ f16x2 h2u(uint32_t u) {
    f16x2 r; __builtin_memcpy(&r, &u, 4); return r;
}
static __device__ __forceinline__ f16x2 pk(float a, float b) {
    return __builtin_amdgcn_cvt_pkrtz(a, b);   // v_cvt_pkrtz_f16_f32
}
static __device__ __forceinline__ f16x2 fma2(f16x2 a, f16x2 b, f16x2 c) {
    return __builtin_elementwise_fma(a, b, c); // v_pk_fma_f16
}
static __device__ __forceinline__ f16x2 relu2(f16x2 a) {
    const f16x2 z = {(__fp16)0.f, (__fp16)0.f};
    return __builtin_elementwise_max(a, z);    // v_pk_max_f16
}
static __device__ __forceinline__ uint32_t splat16(float x) {
    __fp16 h = (__fp16)x;                      // RNE
    uint16_t u; __builtin_memcpy(&u, &h, 2);
    return (uint32_t)u | ((uint32_t)u << 16);
}

__global__ __launch_bounds__(256)
void seg_dice_main(const float* __restrict__ seg_feat,
                   const float* __restrict__ conv_weight,
                   const float* __restrict__ mask,
                   const int*   __restrict__ ind,
                   const float* __restrict__ target,
                   float* __restrict__ ws) {
    // XCD-chunked id: the 16 chunks of one bn land on the same XCD (gather L2 reuse)
    const int g     = (blockIdx.x & 7) * (NBLK / 8) + (blockIdx.x >> 3);
    const int bn    = g >> 4;
    const int chunk = g & (CHUNKS - 1);
    const int b     = bn >> 6;
    const int tid   = threadIdx.x;

    // splat-f16x2 weight tables, rows padded to 12 u32 = 48 B (16B-aligned rows)
    __shared__ uint32_t W1u[8][12];   // [o][0..9]=w1, [10]=b1, [11]=pad
    __shared__ uint32_t W2u[8][12];   // [o][0..7]=w2, [8]=b2
    __shared__ uint32_t W3u[12];      // [0..7]=w3, [8]=b3

    const int ind_bn = ind[bn];
    const float* wsrc = conv_weight + (size_t)b * Dd * HW + ind_bn;

    if (tid < 204) {
        int d = -1;
        uint32_t* dst;
        if (tid < 96)       { int o = tid / 12, i = tid % 12;      dst = &W1u[o][i];
                              if (i < 10) d = o * 10 + i; else if (i == 10) d = 80 + o; }
        else if (tid < 192) { int t = tid - 96; int o = t / 12, i = t % 12; dst = &W2u[o][i];
                              if (i < 8) d = 88 + o * 8 + i; else if (i == 8) d = 152 + o; }
        else                { int i = tid - 192;                   dst = &W3u[i];
                              if (i < 8) d = 160 + i; else if (i == 8) d = 168; }
        uint32_t v = 0;
        if (d >= 0) v = splat16(wsrc[(size_t)d * HW]);
        *dst = v;
    }
    __syncthreads();

    const float m  = mask[bn];
    const float x0 = (float)(ind_bn & (Ww - 1));
    const float y0 = (float)(ind_bn >> 7);

    const float* seg_b  = seg_feat + (size_t)b * Cc * HW;
    const float* tgt_bn = target   + (size_t)bn * HW;

    const int p = chunk * PXB + (tid << 2);      // 4 consecutive px, same row (4 | 128)

    const float4 t4 = *(const float4*)(tgt_bn + p);
    f16x2 fA[8], fB[8];
    #pragma unroll
    for (int c = 0; c < 8; ++c) {
        const float4 v = *(const float4*)(seg_b + c * HW + p);
        fA[c] = pk(v.x, v.y);
        fB[c] = pk(v.z, v.w);
    }

    const float yrf = ((float)(p >> 7) - y0) * INV128;
    const float xbf = ((float)(p & (Ww - 1)) - x0) * INV128;
    const f16x2 yr2  = pk(yrf, yrf);                              // exact k/128
    const f16x2 xr01 = pk(xbf, xbf + INV128);
    const f16x2 xr23 = pk(xbf + 2.f * INV128, xbf + 3.f * INV128);

    // ---- layer 1: 10 -> 8, relu (pk f16) ----
    f16x2 h1A[8], h1B[8];
    #pragma unroll
    for (int o = 0; o < 8; ++o) {
        const uint4* r = reinterpret_cast<const uint4*>(&W1u[o][0]);
        const uint4 qa = r[0], qb = r[1], qc = r[2];
        const f16x2 base = fma2(h2u(qc.y), yr2, h2u(qc.z));       // w9*yr + b1
        f16x2 a01 = fma2(h2u(qc.x), xr01, base);
        f16x2 a23 = fma2(h2u(qc.x), xr23, base);
        a01 = fma2(h2u(qa.x), fA[0], a01);  a23 = fma2(h2u(qa.x), fB[0], a23);
        a01 = fma2(h2u(qa.y), fA[1], a01);  a23 = fma2(h2u(qa.y), fB[1], a23);
        a01 = fma2(h2u(qa.z), fA[2], a01);  a23 = fma2(h2u(qa.z), fB[2], a23);
        a01 = fma2(h2u(qa.w), fA[3], a01);  a23 = fma2(h2u(qa.w), fB[3], a23);
        a01 = fma2(h2u(qb.x), fA[4], a01);  a23 = fma2(h2u(qb.x), fB[4], a23);
        a01 = fma2(h2u(qb.y), fA[5], a01);  a23 = fma2(h2u(qb.y), fB[5], a23);
        a01 = fma2(h2u(qb.z), fA[6], a01);  a23 = fma2(h2u(qb.z), fB[6], a23);
        a01 = fma2(h2u(qb.w), fA[7], a01);  a23 = fma2(h2u(qb.w), fB[7], a23);
        h1A[o] = relu2(a01);
        h1B[o] = relu2(a23);
    }

    // ---- layer 2: 8 -> 8, relu (pk f16) ----
    f16x2 h2A[8], h2B[8];
    #pragma unroll
    for (int o = 0; o < 8; ++o) {
        const uint4* r = reinterpret_cast<const uint4*>(&W2u[o][0]);
        const uint4 qa = r[0], qb = r[1], qc = r[2];
        f16x2 a01 = fma2(h2u(qa.x), h1A[0], h2u(qc.x));           // w0*h + b2
        f16x2 a23 = fma2(h2u(qa.x), h1B[0], h2u(qc.x));
        a01 = fma2(h2u(qa.y), h1A[1], a01);  a23 = fma2(h2u(qa.y), h1B[1], a23);
        a01 = fma2(h2u(qa.z), h1A[2], a01);  a23 = fma2(h2u(qa.z), h1B[2], a23);
        a01 = fma2(h2u(qa.w), h1A[3], a01);  a23 = fma2(h2u(qa.w), h1B[3], a23);
        a01 = fma2(h2u(qb.x), h1A[4], a01);  a23 = fma2(h2u(qb.x), h1B[4], a23);
        a01 = fma2(h2u(qb.y), h1A[5], a01);  a23 = fma2(h2u(qb.y), h1B[5], a23);
        a01 = fma2(h2u(qb.z), h1A[6], a01);  a23 = fma2(h2u(qb.z), h1B[6], a23);
        a01 = fma2(h2u(qb.w), h1A[7], a01);  a23 = fma2(h2u(qb.w), h1B[7], a23);
        h2A[o] = relu2(a01);
        h2B[o] = relu2(a23);
    }

    // ---- layer 3: 8 -> 1 (pk f16), sigmoid + dice in f32 ----
    {
        const uint4* r = reinterpret_cast<const uint4*>(&W3u[0]);
        const uint4 qa = r[0], qb = r[1], qc = r[2];
        f16x2 z01 = fma2(h2u(qa.x), h2A[0], h2u(qc.x));           // w0*h + b3
        f16x2 z23 = fma2(h2u(qa.x), h2B[0], h2u(qc.x));
        z01 = fma2(h2u(qa.y), h2A[1], z01);  z23 = fma2(h2u(qa.y), h2B[1], z23);
        z01 = fma2(h2u(qa.z), h2A[2], z01);  z23 = fma2(h2u(qa.z), h2B[2], z23);
        z01 = fma2(h2u(qa.w), h2A[3], z01);  z23 = fma2(h2u(qa.w), h2B[3], z23);
        z01 = fma2(h2u(qb.x), h2A[4], z01);  z23 = fma2(h2u(qb.x), h2B[4], z23);
        z01 = fma2(h2u(qb.y), h2A[5], z01);  z23 = fma2(h2u(qb.y), h2B[5], z23);
        z01 = fma2(h2u(qb.z), h2A[6], z01);  z23 = fma2(h2u(qb.z), h2B[6], z23);
        z01 = fma2(h2u(qb.w), h2A[7], z01);  z23 = fma2(h2u(qb.w), h2B[7], z23);

        const float o0 = __builtin_amdgcn_rcpf(1.f + __expf(-(float)z01.x));
        const float o1 = __builtin_amdgcn_rcpf(1.f + __expf(-(float)z01.y));
        const float o2 = __builtin_amdgcn_rcpf(1.f + __expf(-(float)z23.x));
        const float o3 = __builtin_amdgcn_rcpf(1.f + __expf(-(float)z23.y));

        float inter = 0.f, ps = 0.f, ts = 0.f;
        inter = fmaf(o0, t4.x, inter); inter = fmaf(o1, t4.y, inter);
        inter = fmaf(o2, t4.z, inter); inter = fmaf(o3, t4.w, inter);
        ps = fmaf(o0, o0, ps); ps = fmaf(o1, o1, ps);
        ps = fmaf(o2, o2, ps); ps = fmaf(o3, o3, ps);
        ts = fmaf(t4.x, t4.x, ts); ts = fmaf(t4.y, t4.y, ts);
        ts = fmaf(t4.z, t4.z, ts); ts = fmaf(t4.w, t4.w, ts);

        const float m2 = m * m;
        inter *= m2; ps *= m2; ts *= m2;

        // wave reduce then cross-wave via LDS
        #pragma unroll
        for (int off = 32; off > 0; off >>= 1) {
            inter += __shfl_down(inter, off);
            ps    += __shfl_down(ps,    off);
            ts    += __shfl_down(ts,    off);
        }
        __shared__ float red[3][4];
        const int wave = tid >> 6;
        if ((tid & 63) == 0) { red[0][wave] = inter; red[1][wave] = ps; red[2][wave] = ts; }
        __syncthreads();
        if (tid == 0) {
            const int local = g & 1023;                  // slot within batch b (64 n x 16 chunks)
            ws[(b * 3 + 0) * 1024 + local] = red[0][0] + red[0][1] + red[0][2] + red[0][3];
            ws[(b * 3 + 1) * 1024 + local] = red[1][0] + red[1][1] + red[1][2] + red[1][3];
            ws[(b * 3 + 2) * 1024 + local] = red[2][0] + red[2][1] + red[2][2] + red[2][3];
        }
    }
}

// deterministic epilogue: 24 series x 1024 partials
__global__ void seg_dice_final(const float* __restrict__ ws, float* __restrict__ out) {
    __shared__ float red[24][8];
    __shared__ float vals[24];
    const int tid = threadIdx.x;  // 256 threads
    if (tid < 192) {
        const int s    = tid >> 3;   // 0..23
        const int part = tid & 7;    // 0..7
        const float4* p = (const float4*)(ws + s * 1024 + part * 128);
        float acc = 0.f;
        #pragma unroll
        for (int i = 0; i < 32; ++i) { const float4 v = p[i]; acc += (v.x + v.y) + (v.z + v.w); }
        red[s][part] = acc;
    }
    __syncthreads();
    if (tid < 24) {
        float acc = 0.f;
        #pragma unroll
        for (int i = 0; i < 8; ++i) acc += red[tid][i];
        vals[tid] = acc;
    }
    __syncthreads();
    if (tid == 0) {
        float acc = 0.f;
        #pragma unroll
        for (int b = 0; b < Bb; ++b) {
            const float inter = vals[b * 3 + 0];
            const float p2    = vals[b * 3 + 1];
            const float t2    = vals[b * 3 + 2];
            acc += 1.0f - (2.0f * inter + 1.0f) / (p2 + t2 + 1.0f);
        }
        out[0] = acc * (1.0f / (float)Bb);
    }
}

extern "C" void kernel_launch(void* const* d_in, const int* in_sizes, int n_in,
                              void* d_out, int out_size, void* d_ws, size_t ws_size,
                              hipStream_t stream) {
    const float* seg_feat    = (const float*)d_in[0];
    const float* conv_weight = (const float*)d_in[1];
    const float* mask        = (const float*)d_in[2];
    const int*   ind         = (const int*)d_in[3];
    const float* target      = (const float*)d_in[4];
    float* out = (float*)d_out;
    float* ws  = (float*)d_ws;

    seg_dice_main<<<NBLK, 256, 0, stream>>>(seg_feat, conv_weight, mask, ind, target, ws);
    seg_dice_final<<<1, 256, 0, stream>>>(ws, out);
}